// Round 12
// baseline (304.605 us; speedup 1.0000x reference)
//
#include <hip/hip_runtime.h>
#include <hip/hip_bf16.h>

#define N_NODES 50000
#define N_EDGES 800000
#define N_TOT   850000   // edges + self loops
#define DIM 128
#define HEADS 8
#define CH 16
#define FF 512
#define LN_EPS 1e-5f
#define NEG_SLOPE 0.2f

// CSR build tiling: 4 node partitions x 64 edge chunks (50 KB LDS per block).
// PART=4 (R8: edge-scan cost ~ PART); NCHUNK=64 halves blkh traffic vs 128.
#define CSR_PART 4
#define NCHUNK  64
#define CHUNK_E (N_EDGES / NCHUNK)    // 12500
#define NPP     (N_NODES / CSR_PART)  // 12500
#define NHIST   (CSR_PART * NCHUNK)   // 256
#define NTILE   196                   // ceil(50000/256)

typedef __bf16 bf16x8 __attribute__((ext_vector_type(8)));
typedef float f32x4 __attribute__((ext_vector_type(4)));

__device__ __forceinline__ float bfr2f(unsigned short u) {
  return __uint_as_float(((unsigned)u) << 16);
}
__device__ __forceinline__ unsigned short f2bfr(float f) {
  __hip_bfloat16 h = __float2bfloat16(f);
  return *(unsigned short*)&h;
}
__device__ __forceinline__ float bf2f(__hip_bfloat16 h) { return __bfloat162float(h); }
__device__ __forceinline__ __hip_bfloat16 f2bf(float f) { return __float2bfloat16(f); }

__device__ __forceinline__ bf16x8 ldcvt8(const float* __restrict__ p) {
  const float4 a = ((const float4*)p)[0];
  const float4 b = ((const float4*)p)[1];
  bf16x8 r;
  r[0] = (__bf16)a.x; r[1] = (__bf16)a.y; r[2] = (__bf16)a.z; r[3] = (__bf16)a.w;
  r[4] = (__bf16)b.x; r[5] = (__bf16)b.y; r[6] = (__bf16)b.z; r[7] = (__bf16)b.w;
  return r;
}

__device__ __forceinline__ int ld_src(const int* ei, int mode, int e) {
  int v = mode ? ei[2 * e] : ei[e];
  return min(max(v, 0), N_NODES - 1);
}
__device__ __forceinline__ int ld_dst(const int* ei, int mode, int e) {
  int v = mode ? ei[2 * (N_EDGES + e)] : ei[N_EDGES + e];
  return min(max(v, 0), N_NODES - 1);
}
// per-block int64-vs-int32 detection (uniform scalar loads, no cross-kernel dep)
__device__ __forceinline__ int edge_mode(const int* __restrict__ ei) {
  int any = 0;
  for (int k = 1; k < 64; k += 2) any |= ei[k];
  return (any == 0) ? 1 : 0;
}

__device__ __forceinline__ float expleaky(float v) {
  v = v > 0.f ? v : NEG_SLOPE * v;
  return __expf(v);
}

// ---------------- K1: per-(p,c) LDS histogram + ALL weight bf16 conversion -------
// 256 blocks x 256 threads; each thread converts up to 3 weight elements
// (W1[gi], W2[gi], and Wg[gi] for gi<16384), covering Wg|W1|W2 = 147456 elems.
__global__ __launch_bounds__(256) void k_hist2(const int* __restrict__ ei,
                                               const float* __restrict__ Wg,
                                               const float* __restrict__ W1,
                                               const float* __restrict__ W2,
                                               __hip_bfloat16* __restrict__ wb,
                                               unsigned short* __restrict__ blkh) {
  __shared__ unsigned int hist[NPP];
  int p = blockIdx.x & 3, c = blockIdx.x >> 2;
  int tid = threadIdx.x;
  int gi = blockIdx.x * 256 + tid;          // [0, 65536)
  wb[16384 + gi] = f2bf(W1[gi]);
  wb[81920 + gi] = f2bf(W2[gi]);
  if (gi < 16384) wb[gi] = f2bf(Wg[gi]);
  for (int i = tid; i < NPP; i += 256) hist[i] = 0;
  int m = edge_mode(ei);
  __syncthreads();
  int nlo = p * NPP;
  int e1 = (c + 1) * CHUNK_E;
  for (int e = c * CHUNK_E + tid; e < e1; e += 256) {
    int d = ld_dst(ei, m, e) - nlo;
    if ((unsigned)d < (unsigned)NPP) atomicAdd(&hist[d], 1u);
  }
  __syncthreads();
  unsigned short* dst = blkh + (size_t)c * N_NODES + nlo;
  for (int i = tid; i < NPP; i += 256) dst[i] = (unsigned short)hist[i];
}

// ---------------- K2: xl = bf16( x @ Wg^T ) + a_s/a_d (reads preconverted Wgb) ---
__global__ __launch_bounds__(256) void k_xl(const float* __restrict__ x,
                                            const __hip_bfloat16* __restrict__ Wgb,
                                            const float* __restrict__ att_s,
                                            const float* __restrict__ att_d,
                                            __hip_bfloat16* __restrict__ xl,
                                            float* __restrict__ a_s,
                                            float* __restrict__ a_d) {
  int gid = blockIdx.x * 256 + threadIdx.x;
  int w = gid >> 6;
  if (w >= 3125 * 2) return;
  int l = threadIdx.x & 63, quad = l >> 4, r = l & 15;
  int strip = w >> 1, cc = w & 1;
  const __bf16* wgb = (const __bf16*)Wgb;
  f32x4 acc[4];
#pragma unroll
  for (int t = 0; t < 4; ++t) acc[t] = (f32x4){0.f, 0.f, 0.f, 0.f};
  int arow = strip * 16 + r;
  bf16x8 af[4];
#pragma unroll
  for (int kk = 0; kk < 4; ++kk) af[kk] = ldcvt8(x + arow * DIM + kk * 32 + quad * 8);
#pragma unroll
  for (int kk = 0; kk < 4; ++kk) {
    bf16x8 bfr[4];
#pragma unroll
    for (int t = 0; t < 4; ++t)
      bfr[t] = *(const bf16x8*)(wgb + (cc * 64 + t * 16 + r) * DIM + kk * 32 + quad * 8);
#pragma unroll
    for (int t = 0; t < 4; ++t)
      acc[t] = __builtin_amdgcn_mfma_f32_16x16x32_bf16(af[kk], bfr[t], acc[t], 0, 0, 0);
  }
  float ats[4], atd[4];
#pragma unroll
  for (int t = 0; t < 4; ++t) {
    ats[t] = att_s[(cc * 4 + t) * CH + r];
    atd[t] = att_d[(cc * 4 + t) * CH + r];
  }
#pragma unroll
  for (int t = 0; t < 4; ++t)
#pragma unroll
    for (int j = 0; j < 4; ++j) {
      int row = strip * 16 + quad * 4 + j;
      int col = cc * 64 + t * 16 + r;
      xl[row * DIM + col] = f2bf(acc[t][j]);
      float vs = acc[t][j] * ats[t];
      float vd = acc[t][j] * atd[t];
      vs += __shfl_xor(vs, 1); vd += __shfl_xor(vd, 1);
      vs += __shfl_xor(vs, 2); vd += __shfl_xor(vd, 2);
      vs += __shfl_xor(vs, 4); vd += __shfl_xor(vd, 4);
      vs += __shfl_xor(vs, 8); vd += __shfl_xor(vd, 8);
      if (r == 0) {
        a_s[row * 8 + cc * 4 + t] = vs;
        a_d[row * 8 + cc * 4 + t] = vd;
      }
    }
}

// ---------------- K3a: per-node chunk prefix, 4-way split + tile totals ----------
// 196 blocks x 1024: node nl = tid&255, chunk-group g = tid>>8 (16 chunks each).
__global__ __launch_bounds__(1024) void k_nscan2(unsigned short* __restrict__ blkh,
                                                 int* __restrict__ deg,
                                                 int* __restrict__ tsum) {
  __shared__ int gs[4][256];
  __shared__ int red[4];
  int tid = threadIdx.x;
  int nl = tid & 255, g = tid >> 8;
  int n = blockIdx.x * 256 + nl;
  unsigned short vv[16];
  int gsum = 0;
  if (n < N_NODES) {
    const unsigned short* base = blkh + (size_t)(g * 16) * N_NODES + n;
#pragma unroll
    for (int i = 0; i < 16; ++i) {
      vv[i] = base[(size_t)i * N_NODES];
      gsum += (int)vv[i];
    }
  }
  gs[g][nl] = gsum;
  __syncthreads();
  int gexcl = 0;
#pragma unroll
  for (int j = 0; j < 4; ++j) if (j < g) gexcl += gs[j][nl];
  int total = gs[0][nl] + gs[1][nl] + gs[2][nl] + gs[3][nl];
  if (n < N_NODES) {
    unsigned short* base = blkh + (size_t)(g * 16) * N_NODES + n;
    int run = gexcl;
#pragma unroll
    for (int i = 0; i < 16; ++i) {
      int t = (int)vv[i];
      base[(size_t)i * N_NODES] = (unsigned short)run;
      run += t;
    }
    if (g == 0) deg[n] = total;
  }
  if (g == 0) {
    int val = (n < N_NODES) ? total + 1 : 0;
    int l = tid & 63, wv = tid >> 6;
#pragma unroll
    for (int off = 1; off < 64; off <<= 1) val += __shfl_xor(val, off);
    if (l == 0) red[wv] = val;
  }
  __syncthreads();
  if (tid == 0) tsum[blockIdx.x] = red[0] + red[1] + red[2] + red[3];
}

// ---------------- K3b: offs + self-loop eid, fully parallel ----------------------
__global__ __launch_bounds__(256) void k_offs2(const int* __restrict__ deg,
                                               const int* __restrict__ tsum,
                                               int* __restrict__ offs,
                                               int* __restrict__ eid) {
  __shared__ int wtot[4];
  __shared__ int red[4];
  __shared__ int sbase;
  int tid = threadIdx.x, l = tid & 63, wv = tid >> 6;
  int bid = blockIdx.x;
  int part = (tid < bid) ? tsum[tid] : 0;   // bid <= 195 < 256
#pragma unroll
  for (int off = 1; off < 64; off <<= 1) part += __shfl_xor(part, off);
  if (l == 0) red[wv] = part;
  __syncthreads();
  if (tid == 0) sbase = (red[0] + red[1]) + (red[2] + red[3]);
  __syncthreads();
  int tbase = sbase;
  int n = bid * 256 + tid;
  int v = (n < N_NODES) ? deg[n] + 1 : 0;
  int xx = v;
#pragma unroll
  for (int off = 1; off < 64; off <<= 1) {
    int t = __shfl_up(xx, off);
    if (l >= off) xx += t;
  }
  if (l == 63) wtot[wv] = xx;
  __syncthreads();
  int wbase = 0;
#pragma unroll
  for (int j = 0; j < 4; ++j) if (j < wv) wbase += wtot[j];
  int excl = tbase + wbase + xx - v;
  if (n < N_NODES) {
    offs[n] = excl;
    eid[excl] = n;
    if (n == N_NODES - 1) offs[N_NODES] = excl + v;
  }
}

// ---------------- K4: scatter, LDS-ordinal, no global atomics --------------------
__global__ __launch_bounds__(256) void k_scatter(const int* __restrict__ ei,
                                                 const int* __restrict__ offs,
                                                 const unsigned short* __restrict__ blkh,
                                                 int* __restrict__ eid) {
  __shared__ unsigned int fill[NPP];
  int p = blockIdx.x & 3, c = blockIdx.x >> 2;
  int tid = threadIdx.x;
  for (int i = tid; i < NPP; i += 256) fill[i] = 0;
  int m = edge_mode(ei);
  __syncthreads();
  int nlo = p * NPP;
  const unsigned short* exl = blkh + (size_t)c * N_NODES;
  int e1 = (c + 1) * CHUNK_E;
  for (int e = c * CHUNK_E + tid; e < e1; e += 256) {
    int dg = ld_dst(ei, m, e);
    int d = dg - nlo;
    if ((unsigned)d < (unsigned)NPP) {
      unsigned ord = atomicAdd(&fill[d], 1u);
      int slot = offs[dg] + 1 + (int)exl[dg] + (int)ord;
      eid[slot] = ld_src(ei, m, e);
    }
  }
}

// ---------------- K5: per-node aggregation + LN1, single-pass (R9-proven loop) ---
__global__ __launch_bounds__(256) void k_attn(const int* __restrict__ eid, const int* __restrict__ offs,
                                              const float* __restrict__ a_s,
                                              const float* __restrict__ a_d,
                                              const __hip_bfloat16* __restrict__ xl,
                                              const float* __restrict__ x,
                                              const float* __restrict__ bias,
                                              const float* __restrict__ g1,
                                              const float* __restrict__ be1,
                                              __hip_bfloat16* __restrict__ h1out) {
  int wv = threadIdx.x >> 6, l = threadIdx.x & 63;
  int n = blockIdx.x * 4 + wv;       // 12500*4 == 50000
  int start = offs[n], end = offs[n + 1];
  int h8 = l & 7, sl8 = l >> 3;      // scoring layout: (slot p+sl8, head h8)
  int hq = l >> 3;                   // aggregation head for this lane (cols 2l,2l+1)
  float adv = a_d[n * 8 + h8];

  const char* xlb = (const char*)xl;
  int l4 = 4 * l;
  float sme = 0.f;                   // partial denom for head h8 (slots = sl8 mod 8)
  float A0 = 0.f, A1 = 0.f;          // unnormalized aggregation, head hq
  int p = start;
  for (; p + 8 <= end; p += 8) {
    int s = eid[p + sl8];
    int boff = s << 8;               // byte offset of row s (DIM*2 = 256 B)
    float w = expleaky(a_s[s * 8 + h8] + adv);
    sme += w;
#pragma unroll
    for (int q = 0; q < 8; ++q) {
      int bq = __shfl(boff, q * 8);
      float wq = __shfl(w, q * 8 + hq);
      ushort2 u = *(const ushort2*)(xlb + bq + l4);
      A0 += wq * bfr2f(u.x);
      A1 += wq * bfr2f(u.y);
    }
  }
  int rem = end - p;
  if (rem > 0) {
    int sl = (sl8 < rem) ? sl8 : 0;
    int s = eid[p + sl];
    int boff = s << 8;
    float w = (sl8 < rem) ? expleaky(a_s[s * 8 + h8] + adv) : 0.f;
    sme += w;
    for (int q = 0; q < rem; ++q) {
      int bq = __shfl(boff, q * 8);
      float wq = __shfl(w, q * 8 + hq);
      ushort2 u = *(const ushort2*)(xlb + bq + l4);
      A0 += wq * bfr2f(u.x);
      A1 += wq * bfr2f(u.y);
    }
  }
  sme += __shfl_xor(sme, 8);
  sme += __shfl_xor(sme, 16);
  sme += __shfl_xor(sme, 32);
  float smh = __shfl(sme, hq);
  float inv = 1.f / (smh + 1e-16f);
  float acc0 = A0 * inv;
  float acc1 = A1 * inv;

  float2 xv = *(const float2*)(x + n * DIM + 2 * l);
  float2 bv = *(const float2*)(bias + 2 * l);
  float v0 = acc0 + bv.x + xv.x;
  float v1 = acc1 + bv.y + xv.y;
  float s2 = v0 + v1;
  for (int off = 32; off >= 1; off >>= 1) s2 += __shfl_xor(s2, off);
  float mu = s2 * (1.f / 128.f);
  float d0 = v0 - mu, d1 = v1 - mu;
  float q = d0 * d0 + d1 * d1;
  for (int off = 32; off >= 1; off >>= 1) q += __shfl_xor(q, off);
  float rs = rsqrtf(q * (1.f / 128.f) + LN_EPS);
  float2 gv = *(const float2*)(g1 + 2 * l);
  float2 bev = *(const float2*)(be1 + 2 * l);
  ushort2 o;
  o.x = f2bfr(d0 * rs * gv.x + bev.x);
  o.y = f2bfr(d1 * rs * gv.y + bev.y);
  *(ushort2*)((unsigned short*)h1out + n * DIM + 2 * l) = o;
}

// ---------------- K6a: hid = relu(h1 @ W1^T + b1), blocked-tile bf16 -------------
__global__ __launch_bounds__(256) void k_ffn1(const __hip_bfloat16* __restrict__ h1,
                                              const __hip_bfloat16* __restrict__ W1b,
                                              const float* __restrict__ b1,
                                              __hip_bfloat16* __restrict__ hid,
                                              int row_base) {
  int wv = threadIdx.x >> 6, l = threadIdx.x & 63, quad = l >> 4, r = l & 15;
  int blk = blockIdx.x;
  int base = row_base + blk * 32;
  const __bf16* h1b = (const __bf16*)h1;
  const __bf16* w1 = (const __bf16*)W1b;
  int r0 = min(base + r, N_NODES - 1);
  int r1 = min(base + 16 + r, N_NODES - 1);

  bf16x8 bn[2][4];
#pragma unroll
  for (int kk = 0; kk < 4; ++kk) {
    bn[0][kk] = *(const bf16x8*)(h1b + r0 * DIM + kk * 32 + quad * 8);
    bn[1][kk] = *(const bf16x8*)(h1b + r1 * DIM + kk * 32 + quad * 8);
  }
  f32x4 acc1[8][2];
#pragma unroll
  for (int tm = 0; tm < 8; ++tm)
#pragma unroll
    for (int tn = 0; tn < 2; ++tn) acc1[tm][tn] = (f32x4){0.f, 0.f, 0.f, 0.f};
#pragma unroll
  for (int kk = 0; kk < 4; ++kk) {
    bf16x8 wf[8];
#pragma unroll
    for (int tm = 0; tm < 8; ++tm)
      wf[tm] = *(const bf16x8*)(w1 + (wv * 128 + tm * 16 + r) * DIM + kk * 32 + quad * 8);
#pragma unroll
    for (int tm = 0; tm < 8; ++tm) {
      acc1[tm][0] = __builtin_amdgcn_mfma_f32_16x16x32_bf16(wf[tm], bn[0][kk], acc1[tm][0], 0, 0, 0);
      acc1[tm][1] = __builtin_amdgcn_mfma_f32_16x16x32_bf16(wf[tm], bn[1][kk], acc1[tm][1], 0, 0, 0);
    }
  }
  unsigned short* hb = (unsigned short*)hid;
#pragma unroll
  for (int tm = 0; tm < 8; ++tm) {
    int f0 = wv * 128 + tm * 16 + quad * 4;
    float4 bb = *(const float4*)(b1 + f0);
#pragma unroll
    for (int tn = 0; tn < 2; ++tn) {
      ushort4 o;
      o.x = f2bfr(fmaxf(acc1[tm][tn][0] + bb.x, 0.f));
      o.y = f2bfr(fmaxf(acc1[tm][tn][1] + bb.y, 0.f));
      o.z = f2bfr(fmaxf(acc1[tm][tn][2] + bb.z, 0.f));
      o.w = f2bfr(fmaxf(acc1[tm][tn][3] + bb.w, 0.f));
      int idx = ((blk * 2 + tn) * 64 + wv * 16 + tm * 2 + (quad >> 1)) * 128
                + r * 8 + (quad & 1) * 4;
      *(ushort4*)(hb + idx) = o;
    }
  }
}

// ---------------- K6b: out = LN2(h1 + hid @ W2^T + b2) ---------------------------
__global__ __launch_bounds__(256) void k_ffn2(const __hip_bfloat16* __restrict__ hid,
                                              const __hip_bfloat16* __restrict__ W2b,
                                              const float* __restrict__ b2,
                                              const float* __restrict__ g2,
                                              const float* __restrict__ be2,
                                              const __hip_bfloat16* __restrict__ h1,
                                              float* __restrict__ out,
                                              int row_base) {
  __shared__ float ps[4][2][16], pq[4][2][16];
  int wv = threadIdx.x >> 6, l = threadIdx.x & 63, quad = l >> 4, r = l & 15;
  int blk = blockIdx.x;
  int base = row_base + blk * 32;
  const __bf16* w2 = (const __bf16*)W2b;
  const unsigned short* hb = (const unsigned short*)hid;

  f32x4 acc2[2][2];
#pragma unroll
  for (int s = 0; s < 2; ++s)
#pragma unroll
    for (int tn = 0; tn < 2; ++tn) acc2[s][tn] = (f32x4){0.f, 0.f, 0.f, 0.f};

  const unsigned short* a0base = hb + ((blk * 2 + 0) * 64 + quad) * 128 + r * 8;
  const unsigned short* a1base = hb + ((blk * 2 + 1) * 64 + quad) * 128 + r * 8;
  const __bf16* w2base = w2 + (wv * 32 + r) * FF + quad * 8;

#pragma unroll 4
  for (int ka = 0; ka < 16; ++ka) {
    bf16x8 a0 = *(const bf16x8*)(a0base + ka * 512);
    bf16x8 a1 = *(const bf16x8*)(a1base + ka * 512);
    bf16x8 wa0 = *(const bf16x8*)(w2base + ka * 32);
    bf16x8 wa1 = *(const bf16x8*)(w2base + 16 * FF + ka * 32);
    acc2[0][0] = __builtin_amdgcn_mfma_f32_16x16x32_bf16(a0, wa0, acc2[0][0], 0, 0, 0);
    acc2[0][1] = __builtin_amdgcn_mfma_f32_16x16x32_bf16(a0, wa1, acc2[0][1], 0, 0, 0);
    acc2[1][0] = __builtin_amdgcn_mfma_f32_16x16x32_bf16(a1, wa0, acc2[1][0], 0, 0, 0);
    acc2[1][1] = __builtin_amdgcn_mfma_f32_16x16x32_bf16(a1, wa1, acc2[1][1], 0, 0, 0);
  }
#pragma unroll
  for (int s = 0; s < 2; ++s)
#pragma unroll
    for (int tn = 0; tn < 2; ++tn) {
      int col = wv * 32 + tn * 16 + r;
      float b2c = b2[col];
#pragma unroll
      for (int j = 0; j < 4; ++j) {
        int row = min(base + s * 16 + quad * 4 + j, N_NODES - 1);
        acc2[s][tn][j] += b2c + bf2f(h1[row * DIM + col]);
      }
    }
#pragma unroll
  for (int s = 0; s < 2; ++s)
#pragma unroll
    for (int j = 0; j < 4; ++j) {
      float sm = acc2[s][0][j] + acc2[s][1][j];
      float qm = acc2[s][0][j] * acc2[s][0][j] + acc2[s][1][j] * acc2[s][1][j];
      sm += __shfl_xor(sm, 1); sm += __shfl_xor(sm, 2); sm += __shfl_xor(sm, 4); sm += __shfl_xor(sm, 8);
      qm += __shfl_xor(qm, 1); qm += __shfl_xor(qm, 2); qm += __shfl_xor(qm, 4); qm += __shfl_xor(qm, 8);
      if (r == j) { ps[wv][s][quad * 4 + j] = sm; pq[wv][s][quad * 4 + j] = qm; }
    }
  __syncthreads();
#pragma unroll
  for (int s = 0; s < 2; ++s)
#pragma unroll
    for (int j = 0; j < 4; ++j) {
      int row16 = quad * 4 + j;
      float st = (ps[0][s][row16] + ps[1][s][row16]) + (ps[2][s][row16] + ps[3][s][row16]);
      float qt = (pq[0][s][row16] + pq[1][s][row16]) + (pq[2][s][row16] + pq[3][s][row16]);
      float mu = st * (1.f / 128.f);
      float var = qt * (1.f / 128.f) - mu * mu;
      float rs = rsqrtf(var + LN_EPS);
      int grow = base + s * 16 + row16;
      if (grow < N_NODES) {
#pragma unroll
        for (int tn = 0; tn < 2; ++tn) {
          int col = wv * 32 + tn * 16 + r;
          out[grow * DIM + col] = (acc2[s][tn][j] - mu) * rs * g2[col] + be2[col];
        }
      }
    }
}

// ---------------- workspace layout (bytes, 256-aligned) --------------------------
#define OFF_H1     0u
#define SZ_H1      (50016u * DIM * 2u)                // 12,804,096
#define OFF_WB     (OFF_H1 + SZ_H1)                   // 12,804,096
#define SZ_WB      294912u                            // Wg|W1|W2 bf16
#define OFF_XL     (OFF_WB + SZ_WB)                   // 13,099,008
#define SZ_XL      (N_NODES * DIM * 2u)               // 12,800,000
#define OFF_AS     (OFF_XL + SZ_XL)                   // 25,899,008
#define SZ_AS      (N_NODES * HEADS * 4u)             // 1,600,000
#define OFF_AD     (OFF_AS + SZ_AS)                   // 27,499,008
#define OFF_DEG    (OFF_AD + SZ_AS)                   // 29,099,008
#define SZ_DEG     200192u
#define OFF_OFFS   (OFF_DEG + SZ_DEG)                 // 29,299,200
#define SZ_OFFS    200448u
#define OFF_EID    (OFF_OFFS + SZ_OFFS)               // 29,499,648
#define SZ_EID     3400192u                           // 850048 * 4
#define OFF_BLKH   (OFF_EID + SZ_EID)                 // 32,899,840
#define SZ_BLKH    (NCHUNK * (unsigned)N_NODES * 2u)  // 6,400,000
#define OFF_TSUM   (OFF_BLKH + SZ_BLKH)               // 39,299,840
// hid aliases [OFF_XL, ...): xl/a_s/a_d/deg/offs/eid/blkh/tsum dead by k_ffn1.
#define OFF_HID    OFF_XL
#define SZ_HID_FULL  (50016u * FF * 2u)               // 51,216,384 -> needs 64,315,392
#define FFN_CHUNK0_BLOCKS 782
#define FFN_CHUNK1_BLOCKS 781
#define FFN_CHUNK0_ROWS   (FFN_CHUNK0_BLOCKS * 32)    // 25024

extern "C" void kernel_launch(void* const* d_in, const int* in_sizes, int n_in,
                              void* d_out, int out_size, void* d_ws, size_t ws_size,
                              hipStream_t stream) {
  const float* x     = (const float*)d_in[0];
  const int*   ei    = (const int*)d_in[1];
  const float* Wg    = (const float*)d_in[2];
  const float* att_s = (const float*)d_in[3];
  const float* att_d = (const float*)d_in[4];
  const float* bias  = (const float*)d_in[5];
  const float* W1    = (const float*)d_in[6];
  const float* b1    = (const float*)d_in[7];
  const float* W2    = (const float*)d_in[8];
  const float* b2    = (const float*)d_in[9];
  const float* g1    = (const float*)d_in[10];
  const float* be1   = (const float*)d_in[11];
  const float* g2    = (const float*)d_in[12];
  const float* be2   = (const float*)d_in[13];

  char* ws = (char*)d_ws;
  __hip_bfloat16* h1     = (__hip_bfloat16*)(ws + OFF_H1);
  __hip_bfloat16* wbuf   = (__hip_bfloat16*)(ws + OFF_WB);
  __hip_bfloat16* Wgb    = wbuf;                      // elems [0, 16384)
  __hip_bfloat16* W1b    = wbuf + 16384;              // elems [16384, 81920)
  __hip_bfloat16* W2b    = wbuf + 81920;              // elems [81920, 147456)
  __hip_bfloat16* xl     = (__hip_bfloat16*)(ws + OFF_XL);
  float*          a_s    = (float*)(ws + OFF_AS);
  float*          a_d    = (float*)(ws + OFF_AD);
  int*            deg    = (int*)(ws + OFF_DEG);
  int*            offs   = (int*)(ws + OFF_OFFS);
  int*            eid    = (int*)(ws + OFF_EID);
  unsigned short* blkh   = (unsigned short*)(ws + OFF_BLKH);
  int*            tsum   = (int*)(ws + OFF_TSUM);
  __hip_bfloat16* hid    = (__hip_bfloat16*)(ws + OFF_HID);
  float*          out    = (float*)d_out;

  // 1) histogram + ALL weight conversion (first; independent of k_xl)
  k_hist2  <<<NHIST,  256, 0, stream>>>(ei, Wg, W1, W2, wbuf, blkh);
  // 2) xl GEMM + scores (reads preconverted bf16 Wg)
  k_xl     <<<1563,   256, 0, stream>>>(x, Wgb, att_s, att_d, xl, a_s, a_d);
  // 3) CSR mid-section (parallelized)
  k_nscan2 <<<NTILE, 1024, 0, stream>>>(blkh, deg, tsum);
  k_offs2  <<<NTILE,  256, 0, stream>>>(deg, tsum, offs, eid);
  k_scatter<<<NHIST,  256, 0, stream>>>(ei, offs, blkh, eid);
  // 4) attention aggregation + LN1
  k_attn   <<<12500,  256, 0, stream>>>(eid, offs, a_s, a_d, xl, x, bias, g1, be1, h1);
  // 5) FFN (full-size hid if workspace permits; else two proven chunks)
  if (ws_size >= (size_t)OFF_HID + SZ_HID_FULL) {
    k_ffn1 <<<1563, 256, 0, stream>>>(h1, W1b, b1, hid, 0);
    k_ffn2 <<<1563, 256, 0, stream>>>(hid, W2b, b2, g2, be2, h1, out, 0);
  } else {
    k_ffn1 <<<FFN_CHUNK0_BLOCKS, 256, 0, stream>>>(h1, W1b, b1, hid, 0);
    k_ffn2 <<<FFN_CHUNK0_BLOCKS, 256, 0, stream>>>(hid, W2b, b2, g2, be2, h1, out, 0);
    k_ffn1 <<<FFN_CHUNK1_BLOCKS, 256, 0, stream>>>(h1, W1b, b1, hid, FFN_CHUNK0_ROWS);
    k_ffn2 <<<FFN_CHUNK1_BLOCKS, 256, 0, stream>>>(hid, W2b, b2, g2, be2, h1, out, FFN_CHUNK0_ROWS);
  }
}

// Round 13
// 289.795 us; speedup vs baseline: 1.0511x; 1.0511x over previous
//
#include <hip/hip_runtime.h>
#include <hip/hip_bf16.h>

#define N_NODES 50000
#define N_EDGES 800000
#define N_TOT   850000   // edges + self loops
#define DIM 128
#define HEADS 8
#define CH 16
#define FF 512
#define LN_EPS 1e-5f
#define NEG_SLOPE 0.2f

// CSR build tiling: 4 node partitions x 128 edge chunks (50 KB LDS per block).
// PART=4, NCHUNK=128 (NHIST=512, 2 blocks/CU) is the measured-best point:
// R8 (PART=16) and R12 (NCHUNK=64) both regressed — waves-in-flight matters.
#define CSR_PART 4
#define NCHUNK  128
#define CHUNK_E (N_EDGES / NCHUNK)    // 6250
#define NPP     (N_NODES / CSR_PART)  // 12500
#define NHIST   (CSR_PART * NCHUNK)   // 512
#define NTILE   196                   // ceil(50000/256)

typedef __bf16 bf16x8 __attribute__((ext_vector_type(8)));
typedef float f32x4 __attribute__((ext_vector_type(4)));

__device__ __forceinline__ float bfr2f(unsigned short u) {
  return __uint_as_float(((unsigned)u) << 16);
}
__device__ __forceinline__ unsigned short f2bfr(float f) {
  __hip_bfloat16 h = __float2bfloat16(f);
  return *(unsigned short*)&h;
}
__device__ __forceinline__ float bf2f(__hip_bfloat16 h) { return __bfloat162float(h); }
__device__ __forceinline__ __hip_bfloat16 f2bf(float f) { return __float2bfloat16(f); }

__device__ __forceinline__ bf16x8 ldcvt8(const float* __restrict__ p) {
  const float4 a = ((const float4*)p)[0];
  const float4 b = ((const float4*)p)[1];
  bf16x8 r;
  r[0] = (__bf16)a.x; r[1] = (__bf16)a.y; r[2] = (__bf16)a.z; r[3] = (__bf16)a.w;
  r[4] = (__bf16)b.x; r[5] = (__bf16)b.y; r[6] = (__bf16)b.z; r[7] = (__bf16)b.w;
  return r;
}

__device__ __forceinline__ int ld_src(const int* ei, int mode, int e) {
  int v = mode ? ei[2 * e] : ei[e];
  return min(max(v, 0), N_NODES - 1);
}
__device__ __forceinline__ int ld_dst(const int* ei, int mode, int e) {
  int v = mode ? ei[2 * (N_EDGES + e)] : ei[N_EDGES + e];
  return min(max(v, 0), N_NODES - 1);
}
// per-block int64-vs-int32 detection (uniform scalar loads, no cross-kernel dep)
__device__ __forceinline__ int edge_mode(const int* __restrict__ ei) {
  int any = 0;
  for (int k = 1; k < 64; k += 2) any |= ei[k];
  return (any == 0) ? 1 : 0;
}

__device__ __forceinline__ float expleaky(float v) {
  v = v > 0.f ? v : NEG_SLOPE * v;
  return __expf(v);
}

// ---------------- K1: per-(p,c) LDS histogram + ALL weight bf16 conversion -------
// 512 blocks x 256 threads cover W1|W2 exactly; first 64 blocks also convert Wg.
__global__ __launch_bounds__(256) void k_hist2(const int* __restrict__ ei,
                                               const float* __restrict__ Wg,
                                               const float* __restrict__ W1,
                                               const float* __restrict__ W2,
                                               __hip_bfloat16* __restrict__ wb,
                                               unsigned short* __restrict__ blkh) {
  __shared__ unsigned int hist[NPP];
  int p = blockIdx.x & 3, c = blockIdx.x >> 2;
  int tid = threadIdx.x;
  int gi = blockIdx.x * 256 + tid;          // [0, 131072)
  if (gi < 65536) wb[16384 + gi] = f2bf(W1[gi]);
  else            wb[16384 + gi] = f2bf(W2[gi - 65536]);
  if (gi < 16384) wb[gi] = f2bf(Wg[gi]);
  for (int i = tid; i < NPP; i += 256) hist[i] = 0;
  int m = edge_mode(ei);
  __syncthreads();
  int nlo = p * NPP;
  int e1 = (c + 1) * CHUNK_E;
  for (int e = c * CHUNK_E + tid; e < e1; e += 256) {
    int d = ld_dst(ei, m, e) - nlo;
    if ((unsigned)d < (unsigned)NPP) atomicAdd(&hist[d], 1u);
  }
  __syncthreads();
  unsigned short* dst = blkh + (size_t)c * N_NODES + nlo;
  for (int i = tid; i < NPP; i += 256) dst[i] = (unsigned short)hist[i];
}

// ---------------- K2: xl = bf16( x @ Wg^T ) + a_s/a_d (reads preconverted Wgb) ---
__global__ __launch_bounds__(256) void k_xl(const float* __restrict__ x,
                                            const __hip_bfloat16* __restrict__ Wgb,
                                            const float* __restrict__ att_s,
                                            const float* __restrict__ att_d,
                                            __hip_bfloat16* __restrict__ xl,
                                            float* __restrict__ a_s,
                                            float* __restrict__ a_d) {
  int gid = blockIdx.x * 256 + threadIdx.x;
  int w = gid >> 6;
  if (w >= 3125 * 2) return;
  int l = threadIdx.x & 63, quad = l >> 4, r = l & 15;
  int strip = w >> 1, cc = w & 1;
  const __bf16* wgb = (const __bf16*)Wgb;
  f32x4 acc[4];
#pragma unroll
  for (int t = 0; t < 4; ++t) acc[t] = (f32x4){0.f, 0.f, 0.f, 0.f};
  int arow = strip * 16 + r;
  bf16x8 af[4];
#pragma unroll
  for (int kk = 0; kk < 4; ++kk) af[kk] = ldcvt8(x + arow * DIM + kk * 32 + quad * 8);
#pragma unroll
  for (int kk = 0; kk < 4; ++kk) {
    bf16x8 bfr[4];
#pragma unroll
    for (int t = 0; t < 4; ++t)
      bfr[t] = *(const bf16x8*)(wgb + (cc * 64 + t * 16 + r) * DIM + kk * 32 + quad * 8);
#pragma unroll
    for (int t = 0; t < 4; ++t)
      acc[t] = __builtin_amdgcn_mfma_f32_16x16x32_bf16(af[kk], bfr[t], acc[t], 0, 0, 0);
  }
  float ats[4], atd[4];
#pragma unroll
  for (int t = 0; t < 4; ++t) {
    ats[t] = att_s[(cc * 4 + t) * CH + r];
    atd[t] = att_d[(cc * 4 + t) * CH + r];
  }
#pragma unroll
  for (int t = 0; t < 4; ++t)
#pragma unroll
    for (int j = 0; j < 4; ++j) {
      int row = strip * 16 + quad * 4 + j;
      int col = cc * 64 + t * 16 + r;
      xl[row * DIM + col] = f2bf(acc[t][j]);
      float vs = acc[t][j] * ats[t];
      float vd = acc[t][j] * atd[t];
      vs += __shfl_xor(vs, 1); vd += __shfl_xor(vd, 1);
      vs += __shfl_xor(vs, 2); vd += __shfl_xor(vd, 2);
      vs += __shfl_xor(vs, 4); vd += __shfl_xor(vd, 4);
      vs += __shfl_xor(vs, 8); vd += __shfl_xor(vd, 8);
      if (r == 0) {
        a_s[row * 8 + cc * 4 + t] = vs;
        a_d[row * 8 + cc * 4 + t] = vd;
      }
    }
}

// ---------------- K3a: per-node chunk prefix, 4-way split + tile totals ----------
__global__ __launch_bounds__(1024) void k_nscan2(unsigned short* __restrict__ blkh,
                                                 int* __restrict__ deg,
                                                 int* __restrict__ tsum) {
  __shared__ int gs[4][256];
  __shared__ int red[4];
  int tid = threadIdx.x;
  int nl = tid & 255, g = tid >> 8;
  int n = blockIdx.x * 256 + nl;
  unsigned short vv[32];
  int gsum = 0;
  if (n < N_NODES) {
    const unsigned short* base = blkh + (size_t)(g * 32) * N_NODES + n;
#pragma unroll
    for (int i = 0; i < 32; ++i) {
      vv[i] = base[(size_t)i * N_NODES];
      gsum += (int)vv[i];
    }
  }
  gs[g][nl] = gsum;
  __syncthreads();
  int gexcl = 0;
#pragma unroll
  for (int j = 0; j < 4; ++j) if (j < g) gexcl += gs[j][nl];
  int total = gs[0][nl] + gs[1][nl] + gs[2][nl] + gs[3][nl];
  if (n < N_NODES) {
    unsigned short* base = blkh + (size_t)(g * 32) * N_NODES + n;
    int run = gexcl;
#pragma unroll
    for (int i = 0; i < 32; ++i) {
      int t = (int)vv[i];
      base[(size_t)i * N_NODES] = (unsigned short)run;
      run += t;
    }
    if (g == 0) deg[n] = total;
  }
  if (g == 0) {
    int val = (n < N_NODES) ? total + 1 : 0;
    int l = tid & 63, wv = tid >> 6;
#pragma unroll
    for (int off = 1; off < 64; off <<= 1) val += __shfl_xor(val, off);
    if (l == 0) red[wv] = val;
  }
  __syncthreads();
  if (tid == 0) tsum[blockIdx.x] = red[0] + red[1] + red[2] + red[3];
}

// ---------------- K3b: offs + self-loop eid, fully parallel ----------------------
__global__ __launch_bounds__(256) void k_offs2(const int* __restrict__ deg,
                                               const int* __restrict__ tsum,
                                               int* __restrict__ offs,
                                               int* __restrict__ eid) {
  __shared__ int wtot[4];
  __shared__ int red[4];
  __shared__ int sbase;
  int tid = threadIdx.x, l = tid & 63, wv = tid >> 6;
  int bid = blockIdx.x;
  int part = (tid < bid) ? tsum[tid] : 0;   // bid <= 195 < 256
#pragma unroll
  for (int off = 1; off < 64; off <<= 1) part += __shfl_xor(part, off);
  if (l == 0) red[wv] = part;
  __syncthreads();
  if (tid == 0) sbase = (red[0] + red[1]) + (red[2] + red[3]);
  __syncthreads();
  int tbase = sbase;
  int n = bid * 256 + tid;
  int v = (n < N_NODES) ? deg[n] + 1 : 0;
  int xx = v;
#pragma unroll
  for (int off = 1; off < 64; off <<= 1) {
    int t = __shfl_up(xx, off);
    if (l >= off) xx += t;
  }
  if (l == 63) wtot[wv] = xx;
  __syncthreads();
  int wbase = 0;
#pragma unroll
  for (int j = 0; j < 4; ++j) if (j < wv) wbase += wtot[j];
  int excl = tbase + wbase + xx - v;
  if (n < N_NODES) {
    offs[n] = excl;
    eid[excl] = n;
    if (n == N_NODES - 1) offs[N_NODES] = excl + v;
  }
}

// ---------------- K4: scatter, LDS-ordinal, no global atomics --------------------
__global__ __launch_bounds__(256) void k_scatter(const int* __restrict__ ei,
                                                 const int* __restrict__ offs,
                                                 const unsigned short* __restrict__ blkh,
                                                 int* __restrict__ eid) {
  __shared__ unsigned int fill[NPP];
  int p = blockIdx.x & 3, c = blockIdx.x >> 2;
  int tid = threadIdx.x;
  for (int i = tid; i < NPP; i += 256) fill[i] = 0;
  int m = edge_mode(ei);
  __syncthreads();
  int nlo = p * NPP;
  const unsigned short* exl = blkh + (size_t)c * N_NODES;
  int e1 = (c + 1) * CHUNK_E;
  for (int e = c * CHUNK_E + tid; e < e1; e += 256) {
    int dg = ld_dst(ei, m, e);
    int d = dg - nlo;
    if ((unsigned)d < (unsigned)NPP) {
      unsigned ord = atomicAdd(&fill[d], 1u);
      int slot = offs[dg] + 1 + (int)exl[dg] + (int)ord;
      eid[slot] = ld_src(ei, m, e);
    }
  }
}

// ---------------- K5: per-node aggregation + LN1, single-pass --------------------
__global__ __launch_bounds__(256) void k_attn(const int* __restrict__ eid, const int* __restrict__ offs,
                                              const float* __restrict__ a_s,
                                              const float* __restrict__ a_d,
                                              const __hip_bfloat16* __restrict__ xl,
                                              const float* __restrict__ x,
                                              const float* __restrict__ bias,
                                              const float* __restrict__ g1,
                                              const float* __restrict__ be1,
                                              __hip_bfloat16* __restrict__ h1out) {
  int wv = threadIdx.x >> 6, l = threadIdx.x & 63;
  int n = blockIdx.x * 4 + wv;       // 12500*4 == 50000
  int start = offs[n], end = offs[n + 1];
  int h8 = l & 7, sl8 = l >> 3;      // scoring layout: (slot p+sl8, head h8)
  int hq = l >> 3;                   // aggregation head for this lane (cols 2l,2l+1)
  float adv = a_d[n * 8 + h8];

  const char* xlb = (const char*)xl;
  int l4 = 4 * l;
  float sme = 0.f;                   // partial denom for head h8 (slots = sl8 mod 8)
  float A0 = 0.f, A1 = 0.f;          // unnormalized aggregation, head hq
  int p = start;
  for (; p + 8 <= end; p += 8) {
    int s = eid[p + sl8];
    int boff = s << 8;               // byte offset of row s (DIM*2 = 256 B)
    float w = expleaky(a_s[s * 8 + h8] + adv);
    sme += w;
#pragma unroll
    for (int q = 0; q < 8; ++q) {
      int bq = __shfl(boff, q * 8);
      float wq = __shfl(w, q * 8 + hq);
      ushort2 u = *(const ushort2*)(xlb + bq + l4);
      A0 += wq * bfr2f(u.x);
      A1 += wq * bfr2f(u.y);
    }
  }
  int rem = end - p;
  if (rem > 0) {
    int sl = (sl8 < rem) ? sl8 : 0;
    int s = eid[p + sl];
    int boff = s << 8;
    float w = (sl8 < rem) ? expleaky(a_s[s * 8 + h8] + adv) : 0.f;
    sme += w;
    for (int q = 0; q < rem; ++q) {
      int bq = __shfl(boff, q * 8);
      float wq = __shfl(w, q * 8 + hq);
      ushort2 u = *(const ushort2*)(xlb + bq + l4);
      A0 += wq * bfr2f(u.x);
      A1 += wq * bfr2f(u.y);
    }
  }
  sme += __shfl_xor(sme, 8);
  sme += __shfl_xor(sme, 16);
  sme += __shfl_xor(sme, 32);
  float smh = __shfl(sme, hq);
  float inv = 1.f / (smh + 1e-16f);
  float acc0 = A0 * inv;
  float acc1 = A1 * inv;

  float2 xv = *(const float2*)(x + n * DIM + 2 * l);
  float2 bv = *(const float2*)(bias + 2 * l);
  float v0 = acc0 + bv.x + xv.x;
  float v1 = acc1 + bv.y + xv.y;
  float s2 = v0 + v1;
  for (int off = 32; off >= 1; off >>= 1) s2 += __shfl_xor(s2, off);
  float mu = s2 * (1.f / 128.f);
  float d0 = v0 - mu, d1 = v1 - mu;
  float q = d0 * d0 + d1 * d1;
  for (int off = 32; off >= 1; off >>= 1) q += __shfl_xor(q, off);
  float rs = rsqrtf(q * (1.f / 128.f) + LN_EPS);
  float2 gv = *(const float2*)(g1 + 2 * l);
  float2 bev = *(const float2*)(be1 + 2 * l);
  ushort2 o;
  o.x = f2bfr(d0 * rs * gv.x + bev.x);
  o.y = f2bfr(d1 * rs * gv.y + bev.y);
  *(ushort2*)((unsigned short*)h1out + n * DIM + 2 * l) = o;
}

// ---------------- K6a: hid = relu(h1 @ W1^T + b1), blocked-tile bf16 -------------
__global__ __launch_bounds__(256) void k_ffn1(const __hip_bfloat16* __restrict__ h1,
                                              const __hip_bfloat16* __restrict__ W1b,
                                              const float* __restrict__ b1,
                                              __hip_bfloat16* __restrict__ hid,
                                              int row_base) {
  int wv = threadIdx.x >> 6, l = threadIdx.x & 63, quad = l >> 4, r = l & 15;
  int blk = blockIdx.x;
  int base = row_base + blk * 32;
  const __bf16* h1b = (const __bf16*)h1;
  const __bf16* w1 = (const __bf16*)W1b;
  int r0 = min(base + r, N_NODES - 1);
  int r1 = min(base + 16 + r, N_NODES - 1);

  bf16x8 bn[2][4];
#pragma unroll
  for (int kk = 0; kk < 4; ++kk) {
    bn[0][kk] = *(const bf16x8*)(h1b + r0 * DIM + kk * 32 + quad * 8);
    bn[1][kk] = *(const bf16x8*)(h1b + r1 * DIM + kk * 32 + quad * 8);
  }
  f32x4 acc1[8][2];
#pragma unroll
  for (int tm = 0; tm < 8; ++tm)
#pragma unroll
    for (int tn = 0; tn < 2; ++tn) acc1[tm][tn] = (f32x4){0.f, 0.f, 0.f, 0.f};
#pragma unroll
  for (int kk = 0; kk < 4; ++kk) {
    bf16x8 wf[8];
#pragma unroll
    for (int tm = 0; tm < 8; ++tm)
      wf[tm] = *(const bf16x8*)(w1 + (wv * 128 + tm * 16 + r) * DIM + kk * 32 + quad * 8);
#pragma unroll
    for (int tm = 0; tm < 8; ++tm) {
      acc1[tm][0] = __builtin_amdgcn_mfma_f32_16x16x32_bf16(wf[tm], bn[0][kk], acc1[tm][0], 0, 0, 0);
      acc1[tm][1] = __builtin_amdgcn_mfma_f32_16x16x32_bf16(wf[tm], bn[1][kk], acc1[tm][1], 0, 0, 0);
    }
  }
  unsigned short* hb = (unsigned short*)hid;
#pragma unroll
  for (int tm = 0; tm < 8; ++tm) {
    int f0 = wv * 128 + tm * 16 + quad * 4;
    float4 bb = *(const float4*)(b1 + f0);
#pragma unroll
    for (int tn = 0; tn < 2; ++tn) {
      ushort4 o;
      o.x = f2bfr(fmaxf(acc1[tm][tn][0] + bb.x, 0.f));
      o.y = f2bfr(fmaxf(acc1[tm][tn][1] + bb.y, 0.f));
      o.z = f2bfr(fmaxf(acc1[tm][tn][2] + bb.z, 0.f));
      o.w = f2bfr(fmaxf(acc1[tm][tn][3] + bb.w, 0.f));
      int idx = ((blk * 2 + tn) * 64 + wv * 16 + tm * 2 + (quad >> 1)) * 128
                + r * 8 + (quad & 1) * 4;
      *(ushort4*)(hb + idx) = o;
    }
  }
}

// ---------------- K6b: out = LN2(h1 + hid @ W2^T + b2) ---------------------------
__global__ __launch_bounds__(256) void k_ffn2(const __hip_bfloat16* __restrict__ hid,
                                              const __hip_bfloat16* __restrict__ W2b,
                                              const float* __restrict__ b2,
                                              const float* __restrict__ g2,
                                              const float* __restrict__ be2,
                                              const __hip_bfloat16* __restrict__ h1,
                                              float* __restrict__ out,
                                              int row_base) {
  __shared__ float ps[4][2][16], pq[4][2][16];
  int wv = threadIdx.x >> 6, l = threadIdx.x & 63, quad = l >> 4, r = l & 15;
  int blk = blockIdx.x;
  int base = row_base + blk * 32;
  const __bf16* w2 = (const __bf16*)W2b;
  const unsigned short* hb = (const unsigned short*)hid;

  f32x4 acc2[2][2];
#pragma unroll
  for (int s = 0; s < 2; ++s)
#pragma unroll
    for (int tn = 0; tn < 2; ++tn) acc2[s][tn] = (f32x4){0.f, 0.f, 0.f, 0.f};

  const unsigned short* a0base = hb + ((blk * 2 + 0) * 64 + quad) * 128 + r * 8;
  const unsigned short* a1base = hb + ((blk * 2 + 1) * 64 + quad) * 128 + r * 8;
  const __bf16* w2base = w2 + (wv * 32 + r) * FF + quad * 8;

#pragma unroll 4
  for (int ka = 0; ka < 16; ++ka) {
    bf16x8 a0 = *(const bf16x8*)(a0base + ka * 512);
    bf16x8 a1 = *(const bf16x8*)(a1base + ka * 512);
    bf16x8 wa0 = *(const bf16x8*)(w2base + ka * 32);
    bf16x8 wa1 = *(const bf16x8*)(w2base + 16 * FF + ka * 32);
    acc2[0][0] = __builtin_amdgcn_mfma_f32_16x16x32_bf16(a0, wa0, acc2[0][0], 0, 0, 0);
    acc2[0][1] = __builtin_amdgcn_mfma_f32_16x16x32_bf16(a0, wa1, acc2[0][1], 0, 0, 0);
    acc2[1][0] = __builtin_amdgcn_mfma_f32_16x16x32_bf16(a1, wa0, acc2[1][0], 0, 0, 0);
    acc2[1][1] = __builtin_amdgcn_mfma_f32_16x16x32_bf16(a1, wa1, acc2[1][1], 0, 0, 0);
  }
#pragma unroll
  for (int s = 0; s < 2; ++s)
#pragma unroll
    for (int tn = 0; tn < 2; ++tn) {
      int col = wv * 32 + tn * 16 + r;
      float b2c = b2[col];
#pragma unroll
      for (int j = 0; j < 4; ++j) {
        int row = min(base + s * 16 + quad * 4 + j, N_NODES - 1);
        acc2[s][tn][j] += b2c + bf2f(h1[row * DIM + col]);
      }
    }
#pragma unroll
  for (int s = 0; s < 2; ++s)
#pragma unroll
    for (int j = 0; j < 4; ++j) {
      float sm = acc2[s][0][j] + acc2[s][1][j];
      float qm = acc2[s][0][j] * acc2[s][0][j] + acc2[s][1][j] * acc2[s][1][j];
      sm += __shfl_xor(sm, 1); sm += __shfl_xor(sm, 2); sm += __shfl_xor(sm, 4); sm += __shfl_xor(sm, 8);
      qm += __shfl_xor(qm, 1); qm += __shfl_xor(qm, 2); qm += __shfl_xor(qm, 4); qm += __shfl_xor(qm, 8);
      if (r == j) { ps[wv][s][quad * 4 + j] = sm; pq[wv][s][quad * 4 + j] = qm; }
    }
  __syncthreads();
#pragma unroll
  for (int s = 0; s < 2; ++s)
#pragma unroll
    for (int j = 0; j < 4; ++j) {
      int row16 = quad * 4 + j;
      float st = (ps[0][s][row16] + ps[1][s][row16]) + (ps[2][s][row16] + ps[3][s][row16]);
      float qt = (pq[0][s][row16] + pq[1][s][row16]) + (pq[2][s][row16] + pq[3][s][row16]);
      float mu = st * (1.f / 128.f);
      float var = qt * (1.f / 128.f) - mu * mu;
      float rs = rsqrtf(var + LN_EPS);
      int grow = base + s * 16 + row16;
      if (grow < N_NODES) {
#pragma unroll
        for (int tn = 0; tn < 2; ++tn) {
          int col = wv * 32 + tn * 16 + r;
          out[grow * DIM + col] = (acc2[s][tn][j] - mu) * rs * g2[col] + be2[col];
        }
      }
    }
}

// ---------------- workspace layout (bytes, 256-aligned) --------------------------
#define OFF_H1     0u
#define SZ_H1      (50016u * DIM * 2u)                // 12,804,096
#define OFF_WB     (OFF_H1 + SZ_H1)                   // 12,804,096
#define SZ_WB      294912u                            // Wg|W1|W2 bf16
#define OFF_XL     (OFF_WB + SZ_WB)                   // 13,099,008
#define SZ_XL      (N_NODES * DIM * 2u)               // 12,800,000
#define OFF_AS     (OFF_XL + SZ_XL)                   // 25,899,008
#define SZ_AS      (N_NODES * HEADS * 4u)             // 1,600,000
#define OFF_AD     (OFF_AS + SZ_AS)                   // 27,499,008
#define OFF_DEG    (OFF_AD + SZ_AS)                   // 29,099,008
#define SZ_DEG     200192u
#define OFF_OFFS   (OFF_DEG + SZ_DEG)                 // 29,299,200
#define SZ_OFFS    200448u
#define OFF_EID    (OFF_OFFS + SZ_OFFS)               // 29,499,648
#define SZ_EID     3400192u                           // 850048 * 4
#define OFF_BLKH   (OFF_EID + SZ_EID)                 // 32,899,840
#define SZ_BLKH    (NCHUNK * (unsigned)N_NODES * 2u)  // 12,800,000
#define OFF_TSUM   (OFF_BLKH + SZ_BLKH)               // 45,699,840
// hid aliases [OFF_XL, ...): xl/a_s/a_d/deg/offs/eid/blkh/tsum dead by k_ffn1.
#define OFF_HID    OFF_XL
#define SZ_HID_FULL  (50016u * FF * 2u)               // 51,216,384 -> needs 64,315,392
#define FFN_CHUNK0_BLOCKS 782
#define FFN_CHUNK1_BLOCKS 781
#define FFN_CHUNK0_ROWS   (FFN_CHUNK0_BLOCKS * 32)    // 25024

extern "C" void kernel_launch(void* const* d_in, const int* in_sizes, int n_in,
                              void* d_out, int out_size, void* d_ws, size_t ws_size,
                              hipStream_t stream) {
  const float* x     = (const float*)d_in[0];
  const int*   ei    = (const int*)d_in[1];
  const float* Wg    = (const float*)d_in[2];
  const float* att_s = (const float*)d_in[3];
  const float* att_d = (const float*)d_in[4];
  const float* bias  = (const float*)d_in[5];
  const float* W1    = (const float*)d_in[6];
  const float* b1    = (const float*)d_in[7];
  const float* W2    = (const float*)d_in[8];
  const float* b2    = (const float*)d_in[9];
  const float* g1    = (const float*)d_in[10];
  const float* be1   = (const float*)d_in[11];
  const float* g2    = (const float*)d_in[12];
  const float* be2   = (const float*)d_in[13];

  char* ws = (char*)d_ws;
  __hip_bfloat16* h1     = (__hip_bfloat16*)(ws + OFF_H1);
  __hip_bfloat16* wbuf   = (__hip_bfloat16*)(ws + OFF_WB);
  __hip_bfloat16* Wgb    = wbuf;                      // elems [0, 16384)
  __hip_bfloat16* W1b    = wbuf + 16384;              // elems [16384, 81920)
  __hip_bfloat16* W2b    = wbuf + 81920;              // elems [81920, 147456)
  __hip_bfloat16* xl     = (__hip_bfloat16*)(ws + OFF_XL);
  float*          a_s    = (float*)(ws + OFF_AS);
  float*          a_d    = (float*)(ws + OFF_AD);
  int*            deg    = (int*)(ws + OFF_DEG);
  int*            offs   = (int*)(ws + OFF_OFFS);
  int*            eid    = (int*)(ws + OFF_EID);
  unsigned short* blkh   = (unsigned short*)(ws + OFF_BLKH);
  int*            tsum   = (int*)(ws + OFF_TSUM);
  __hip_bfloat16* hid    = (__hip_bfloat16*)(ws + OFF_HID);
  float*          out    = (float*)d_out;

  // 1) histogram + ALL weight conversion (first; independent of k_xl)
  k_hist2  <<<NHIST,  256, 0, stream>>>(ei, Wg, W1, W2, wbuf, blkh);
  // 2) xl GEMM + scores (reads preconverted bf16 Wg)
  k_xl     <<<1563,   256, 0, stream>>>(x, Wgb, att_s, att_d, xl, a_s, a_d);
  // 3) CSR mid-section (parallelized)
  k_nscan2 <<<NTILE, 1024, 0, stream>>>(blkh, deg, tsum);
  k_offs2  <<<NTILE,  256, 0, stream>>>(deg, tsum, offs, eid);
  k_scatter<<<NHIST,  256, 0, stream>>>(ei, offs, blkh, eid);
  // 4) attention aggregation + LN1
  k_attn   <<<12500,  256, 0, stream>>>(eid, offs, a_s, a_d, xl, x, bias, g1, be1, h1);
  // 5) FFN (full-size hid if workspace permits; else two proven chunks)
  if (ws_size >= (size_t)OFF_HID + SZ_HID_FULL) {
    k_ffn1 <<<1563, 256, 0, stream>>>(h1, W1b, b1, hid, 0);
    k_ffn2 <<<1563, 256, 0, stream>>>(hid, W2b, b2, g2, be2, h1, out, 0);
  } else {
    k_ffn1 <<<FFN_CHUNK0_BLOCKS, 256, 0, stream>>>(h1, W1b, b1, hid, 0);
    k_ffn2 <<<FFN_CHUNK0_BLOCKS, 256, 0, stream>>>(hid, W2b, b2, g2, be2, h1, out, 0);
    k_ffn1 <<<FFN_CHUNK1_BLOCKS, 256, 0, stream>>>(h1, W1b, b1, hid, FFN_CHUNK0_ROWS);
    k_ffn2 <<<FFN_CHUNK1_BLOCKS, 256, 0, stream>>>(hid, W2b, b2, g2, be2, h1, out, FFN_CHUNK0_ROWS);
  }
}